// Round 4
// baseline (603.153 us; speedup 1.0000x reference)
//
#include <hip/hip_runtime.h>
#include <math.h>

#define Bn 4
#define Vn 5
#define Cc 32
#define Hh 256
#define Ww 320
#define DD 4
#define GG 8
#define HW (Hh*Ww)
#define BLOCKS_PER_B (HW/256)                 // 320
#define CHUNKS 4                              // 8 channels per chunk
#define TOTAL_BLOCKS (CHUNKS*Bn*BLOCKS_PER_B) // 5120

// ---------------------------------------------------------------------------
// Prologue: per (b, src_view i=1..4) compute P = src_proj_new @ inv(ref_proj_new)
// ---------------------------------------------------------------------------
__global__ void proj_kernel(const float* __restrict__ proj, float* __restrict__ out12) {
    int t = blockIdx.x * blockDim.x + threadIdx.x;
    if (t >= Bn * (Vn - 1)) return;
    int b = t / (Vn - 1);
    int i = t % (Vn - 1) + 1;

    const float* pb = proj + (size_t)b * Vn * 2 * 16;

    double refm[16], srcm[16];
    {
        const float* E = pb + 0 * 32 + 0;
        const float* K = pb + 0 * 32 + 16;
        for (int r = 0; r < 3; r++)
            for (int c = 0; c < 4; c++) {
                double s = 0.0;
                for (int k = 0; k < 3; k++) s += (double)K[r*4+k] * (double)E[k*4+c];
                refm[r*4+c] = s;
            }
        for (int c = 0; c < 4; c++) refm[12+c] = (double)E[12+c];
    }
    {
        const float* E = pb + i * 32 + 0;
        const float* K = pb + i * 32 + 16;
        for (int r = 0; r < 3; r++)
            for (int c = 0; c < 4; c++) {
                double s = 0.0;
                for (int k = 0; k < 3; k++) s += (double)K[r*4+k] * (double)E[k*4+c];
                srcm[r*4+c] = s;
            }
        for (int c = 0; c < 4; c++) srcm[12+c] = (double)E[12+c];
    }

    double a[16], inv[16];
    for (int k = 0; k < 16; k++) { a[k] = refm[k]; inv[k] = 0.0; }
    inv[0] = inv[5] = inv[10] = inv[15] = 1.0;
    for (int col = 0; col < 4; col++) {
        int piv = col; double best = fabs(a[col*4+col]);
        for (int r = col + 1; r < 4; r++) {
            double v = fabs(a[r*4+col]);
            if (v > best) { best = v; piv = r; }
        }
        if (piv != col) {
            for (int c = 0; c < 4; c++) {
                double tmp = a[col*4+c]; a[col*4+c] = a[piv*4+c]; a[piv*4+c] = tmp;
                tmp = inv[col*4+c]; inv[col*4+c] = inv[piv*4+c]; inv[piv*4+c] = tmp;
            }
        }
        double rd = 1.0 / a[col*4+col];
        for (int c = 0; c < 4; c++) { a[col*4+c] *= rd; inv[col*4+c] *= rd; }
        for (int r = 0; r < 4; r++) {
            if (r == col) continue;
            double f = a[r*4+col];
            for (int c = 0; c < 4; c++) { a[r*4+c] -= f * a[col*4+c]; inv[r*4+c] -= f * inv[col*4+c]; }
        }
    }

    double P[16];
    for (int r = 0; r < 4; r++)
        for (int c = 0; c < 4; c++) {
            double s = 0.0;
            for (int k = 0; k < 4; k++) s += srcm[r*4+k] * inv[k*4+c];
            P[r*4+c] = s;
        }

    float* o = out12 + t * 12;
    o[0] = (float)P[0];  o[1] = (float)P[1];  o[2]  = (float)P[2];
    o[3] = (float)P[4];  o[4] = (float)P[5];  o[5]  = (float)P[6];
    o[6] = (float)P[8];  o[7] = (float)P[9];  o[8]  = (float)P[10];
    o[9] = (float)P[3];  o[10] = (float)P[7]; o[11] = (float)P[11];
}

// ---------------------------------------------------------------------------
// Main kernel: one block per (chunk-of-8-channels, b, 256-pixel row segment).
//  * Channel chunk moved from an in-thread loop to the grid: 5120 blocks =
//    20480 waves (~80 waves/CU of work) -> latency hiding. Homography math
//    was already per-chunk, so VALU duplication is ~0.
//  * XCD swizzle: consecutive physical blocks round-robin XCDs, so
//    logical = (phys%8)*(TOTAL/8) + phys/8 gives each XCD a CONTIGUOUS run
//    of row segments of the same (chunk,b) -> vertically overlapping src
//    rows hit the same XCD's L2 instead of being re-fetched from HBM.
//  * Bilinear via clamped patch origin + per-axis weight remap (round 2).
//  * samp_out written by chunk 0 only.
// ---------------------------------------------------------------------------
__global__ __launch_bounds__(256, 6) void cost_kernel(
    const float* __restrict__ depth_values,
    const float* __restrict__ features,
    const float* __restrict__ depth_interval,
    const float* __restrict__ view_weights,
    const float* __restrict__ P12,
    float* __restrict__ sim_out,
    float* __restrict__ samp_out)
{
    int phys = blockIdx.x;
    int lg   = (phys & 7) * (TOTAL_BLOCKS / 8) + (phys >> 3);
    int chunk = lg / (Bn * BLOCKS_PER_B);
    int rem   = lg - chunk * (Bn * BLOCKS_PER_B);
    int b     = rem / BLOCKS_PER_B;
    int seg   = rem - b * BLOCKS_PER_B;
    int pix   = seg * 256 + threadIdx.x;
    int c0    = chunk * 8;

    int h = pix / Ww;
    int w = pix - h * Ww;

    float inv_d = 1.0f / depth_values[b * HW + pix];
    float itv   = depth_interval[b * HW + pix];
    float dmin  = inv_d - 2.0f * itv;
    float step  = (4.0f * itv) / 3.0f;

    float depth[DD];
    #pragma unroll
    for (int d = 0; d < DD; d++) {
        float s  = dmin + (float)d * step;
        depth[d] = 1.0f / s;
    }
    if (chunk == 0) {
        #pragma unroll
        for (int d = 0; d < DD; d++)
            samp_out[((size_t)b * DD + d) * HW + pix] = depth[d];
    }

    float vw[Vn - 1];
    float wsum = 0.0f;
    #pragma unroll
    for (int i = 0; i < Vn - 1; i++) {
        vw[i] = view_weights[((size_t)b * (Vn - 1) + i) * HW + pix];
        wsum += vw[i];
    }
    float dn = 1.0f / (wsum + 1e-6f);

    const float xf = (float)w, yf = (float)h;

    float ref8[8];
    const float* refp = features + (size_t)b * Vn * Cc * HW + (size_t)c0 * HW + pix;
    #pragma unroll
    for (int j = 0; j < 8; j++) ref8[j] = refp[(size_t)j * HW];

    float acc[2][DD];
    #pragma unroll
    for (int g2 = 0; g2 < 2; g2++)
        #pragma unroll
        for (int d = 0; d < DD; d++) acc[g2][d] = 0.0f;

    #pragma unroll 1
    for (int i = 0; i < Vn - 1; i++) {
        const float* P = P12 + (b * (Vn - 1) + i) * 12;   // uniform -> s_load
        float rx = P[0] * xf + P[1] * yf + P[2];
        float ry = P[3] * xf + P[4] * yf + P[5];
        float rz = P[6] * xf + P[7] * yf + P[8];
        float tx = P[9], ty = P[10], tz = P[11];

        float scale = 0.25f * vw[i];
        const float* src = features + ((size_t)(b * Vn) + (i + 1)) * Cc * HW
                         + (size_t)c0 * HW;

        #pragma unroll
        for (int d = 0; d < DD; d++) {
            float D  = depth[d];
            float px = rx * D + tx;
            float py = ry * D + ty;
            float pz = rz * D + tz;
            float rpz = 1.0f / pz;
            float gx = px * rpz;
            float gy = py * rpz;

            float x0f = floorf(gx);
            float y0f = floorf(gy);
            float wx1 = gx - x0f;
            float wy1 = gy - y0f;
            float wx0 = 1.0f - wx1;
            float wy0 = 1.0f - wy1;

            float xbf = fminf(fmaxf(x0f, 0.0f), (float)(Ww - 2));
            float ybf = fminf(fmaxf(y0f, 0.0f), (float)(Hh - 2));
            float dxf = x0f - xbf;
            float dyf = y0f - ybf;

            float pcx0 = (dxf == 0.0f) ? wx0 : ((dxf == -1.0f) ? wx1 : 0.0f);
            float pcx1 = (dxf == 0.0f) ? wx1 : ((dxf ==  1.0f) ? wx0 : 0.0f);
            float pcy0 = (dyf == 0.0f) ? wy0 : ((dyf == -1.0f) ? wy1 : 0.0f);
            float pcy1 = (dyf == 0.0f) ? wy1 : ((dyf ==  1.0f) ? wy0 : 0.0f);

            float W00 = pcx0 * pcy0 * scale;
            float W10 = pcx1 * pcy0 * scale;
            float W01 = pcx0 * pcy1 * scale;
            float W11 = pcx1 * pcy1 * scale;

            int o00 = (int)ybf * Ww + (int)xbf;

            #pragma unroll
            for (int j = 0; j < 8; j++) {
                const float* p = src + (size_t)j * HW + o00;
                float val = W00 * p[0] + W10 * p[1] + W01 * p[Ww] + W11 * p[Ww + 1];
                acc[j >> 2][d] += val * ref8[j];
            }
        }
    }

    float* so_base = sim_out + (size_t)b * (GG * DD) * HW + pix;
    #pragma unroll
    for (int g2 = 0; g2 < 2; g2++)
        #pragma unroll
        for (int d = 0; d < DD; d++)
            so_base[(size_t)(((c0 >> 2) + g2) * DD + d) * HW] = acc[g2][d] * dn;
}

extern "C" void kernel_launch(void* const* d_in, const int* in_sizes, int n_in,
                              void* d_out, int out_size, void* d_ws, size_t ws_size,
                              hipStream_t stream) {
    const float* depth_values   = (const float*)d_in[0];
    const float* features       = (const float*)d_in[1];
    const float* projm          = (const float*)d_in[2];
    const float* depth_interval = (const float*)d_in[3];
    const float* view_weights   = (const float*)d_in[6];

    float* out      = (float*)d_out;
    float* sim_out  = out;                              // (B, G*DD, H, W)
    float* samp_out = out + (size_t)Bn * GG * DD * HW;  // (B, DD, H, W)
    float* P12      = (float*)d_ws;                     // 16 x 12 floats

    proj_kernel<<<1, 64, 0, stream>>>(projm, P12);
    cost_kernel<<<TOTAL_BLOCKS, 256, 0, stream>>>(
        depth_values, features, depth_interval, view_weights, P12, sim_out, samp_out);
}